// Round 4
// baseline (419.838 us; speedup 1.0000x reference)
//
#include <hip/hip_runtime.h>
#include <hip/hip_bf16.h>

// ---------------------------------------------------------------------------
// AttentionBlockWithSelfAttention on MI355X (gfx950)
// B=4, Cin=128, Fi=64, H=W=64, N=4096, d_qk=8
//
// TWO dispatches (round-3 evidence: ~128us invariant "rest" => dispatch
// overhead, so prep merged into conv via per-lane weight folding, and
// combine merged into attn via split-K last-block-done reduction):
//   k1 conv_fused: c = relu(BN-folded conv), Q/K/V bf16; zeroes counters
//   k2 attn_fused: flash partials (KV split x8) + atomic-counter combine
//                  + fused psi/sigmoid/x*psi epilogue
// ---------------------------------------------------------------------------

typedef short bf16x8 __attribute__((ext_vector_type(8)));
typedef unsigned short u16x8 __attribute__((ext_vector_type(8)));
typedef unsigned short u16x4 __attribute__((ext_vector_type(4)));
typedef float f32x4 __attribute__((ext_vector_type(4)));

__device__ __forceinline__ unsigned short f2b16(float f) {
  return __builtin_bit_cast(unsigned short, __float2bfloat16(f));
}
__device__ __forceinline__ float b2f(unsigned short u) {
  return __bfloat162float(__builtin_bit_cast(__hip_bfloat16, u));
}

#define EPSV 1e-5f

// ---- workspace layout (bytes) ----
#define C_OFF      0u                      // 4*64*4096 bf16 = 2097152
#define Q_OFF      (C_OFF + 2097152u)      // 4*4096*8 bf16 = 262144
#define K_OFF      (Q_OFF + 262144u)
#define V_OFF      (K_OFF + 262144u)       // 4*64*4096 bf16 = 2097152
#define OPART_OFF  (V_OFF + 2097152u)      // 32*4096*64 bf16 = 16777216
#define ML_OFF     (OPART_OFF + 16777216u) // 32*4096*2 f32 = 1048576
#define CNT_OFF    (ML_OFF + 1048576u)     // 256 int

// ===========================================================================
// conv_fused: one block per (b, 32-point tile). 512 blocks, 4 waves.
// BN folding done per-lane in registers (no prep kernel).
__global__ __launch_bounds__(256) void conv_fused_kernel(
    const float* __restrict__ g, const float* __restrict__ x,
    const float* __restrict__ wg_w, const float* __restrict__ wg_b,
    const float* __restrict__ bng_w, const float* __restrict__ bng_b,
    const float* __restrict__ bng_m, const float* __restrict__ bng_v,
    const float* __restrict__ wx_w, const float* __restrict__ wx_b,
    const float* __restrict__ bnx_w, const float* __restrict__ bnx_b,
    const float* __restrict__ bnx_m, const float* __restrict__ bnx_v,
    const float* __restrict__ q_w, const float* __restrict__ q_b,
    const float* __restrict__ k_w, const float* __restrict__ k_b,
    const float* __restrict__ v_w, const float* __restrict__ v_b,
    unsigned short* __restrict__ cb, unsigned short* __restrict__ Qb,
    unsigned short* __restrict__ Kb, unsigned short* __restrict__ Vb,
    int* __restrict__ cnt)
{
  __shared__ __attribute__((aligned(16))) unsigned short xt[32][264];    // [n][k]
  __shared__ __attribute__((aligned(16))) unsigned short clds[32][72];   // [n][o]
  __shared__ __attribute__((aligned(16))) unsigned short vstage[64][36]; // [ch][n]

  const int t = threadIdx.x;
  const int bid = blockIdx.x;
  const int b = bid >> 7;
  const int n0 = (bid & 127) << 5;

  if (bid == 0) cnt[t] = 0;   // split-K counters for attn (stream-ordered)

  // ---- stage [g;x] tile transposed to [n][k] bf16 (128B/row coalesced) ----
  {
    const int col4 = t & 7;          // n offset = col4*4
    const int rowg = t >> 3;         // rows rowg*8 .. +7
    float4 v[8];
    #pragma unroll
    for (int rr = 0; rr < 8; ++rr) {
      int row = rowg * 8 + rr;
      const float* src = (row < 128)
          ? (g + ((size_t)(b * 128 + row)) * 4096 + n0 + col4 * 4)
          : (x + ((size_t)(b * 128 + (row - 128))) * 4096 + n0 + col4 * 4);
      v[rr] = *(const float4*)src;
    }
    #pragma unroll
    for (int j = 0; j < 4; ++j) {
      u16x8 pk;
      #pragma unroll
      for (int rr = 0; rr < 8; ++rr)
        pk[rr] = f2b16(((const float*)&v[rr])[j]);
      *(u16x8*)(&xt[col4 * 4 + j][rowg * 8]) = pk;
    }
  }

  const int l = t & 63, w = t >> 6;
  const int l15 = l & 15, lg = l >> 4;
  f32x4 zf = {0.f, 0.f, 0.f, 0.f};

  // ---- per-lane BN-folded A-fragments for the conv GEMM ----
  const int orow = w * 16 + l15;
  const float invg = bng_w[orow] * rsqrtf(bng_v[orow] + EPSV);
  const float invx = bnx_w[orow] * rsqrtf(bnx_v[orow] + EPSV);
  bf16x8 afrag[8];
  #pragma unroll
  for (int ks = 0; ks < 8; ++ks) {
    int k = ks * 32 + lg * 8;        // 8-chunk never straddles k=128
    const float* wp;
    float sc;
    if (k < 128) { wp = wg_w + orow * 128 + k;        sc = invg; }
    else         { wp = wx_w + orow * 128 + (k - 128); sc = invx; }
    float4 w0 = *(const float4*)wp;
    float4 w1 = *(const float4*)(wp + 4);
    u16x8 pk;
    pk[0] = f2b16(w0.x * sc); pk[1] = f2b16(w0.y * sc);
    pk[2] = f2b16(w0.z * sc); pk[3] = f2b16(w0.w * sc);
    pk[4] = f2b16(w1.x * sc); pk[5] = f2b16(w1.y * sc);
    pk[6] = f2b16(w1.z * sc); pk[7] = f2b16(w1.w * sc);
    afrag[ks] = __builtin_bit_cast(bf16x8, pk);
  }
  __syncthreads();

  // ---- conv MFMA: wave w owns o-rows [16w,16w+16), 2 n-subtiles ----
  f32x4 acc[2];
  acc[0] = acc[1] = zf;
  #pragma unroll
  for (int ks = 0; ks < 8; ++ks) {
    #pragma unroll
    for (int ns = 0; ns < 2; ++ns) {
      bf16x8 bfv = *(const bf16x8*)(&xt[ns * 16 + l15][ks * 32 + lg * 8]);
      acc[ns] = __builtin_amdgcn_mfma_f32_16x16x32_bf16(afrag[ks], bfv, acc[ns], 0, 0, 0);
    }
  }
  #pragma unroll
  for (int r = 0; r < 4; ++r) {
    int o = w * 16 + lg * 4 + r;
    float ig = bng_w[o] * rsqrtf(bng_v[o] + EPSV);
    float ix = bnx_w[o] * rsqrtf(bnx_v[o] + EPSV);
    float bc = (wg_b[o] - bng_m[o]) * ig + bng_b[o]
             + (wx_b[o] - bnx_m[o]) * ix + bnx_b[o];
    #pragma unroll
    for (int ns = 0; ns < 2; ++ns) {
      float cv = fmaxf(acc[ns][r] + bc, 0.f);
      unsigned short cv16 = f2b16(cv);
      cb[((size_t)(b * 64 + o)) * 4096 + n0 + ns * 16 + l15] = cv16;
      clds[ns * 16 + l15][o] = cv16;
    }
  }
  __syncthreads();

  // ---- QKV: 10 tiles (5 row-tiles x 2 n-subtiles) over 4 waves ----
  #pragma unroll
  for (int i = 0; i < 3; ++i) {
    int tau = w + 4 * i;
    if (tau >= 10) break;
    int t5 = tau % 5, ns = tau / 5;
    int wrow = t5 * 16 + l15;
    // fold Wqkv row fragment per-lane (raw bf16 cvt, no BN here)
    f32x4 a2 = zf;
    #pragma unroll
    for (int kk = 0; kk < 2; ++kk) {
      int k = kk * 32 + lg * 8;
      const float* wp = (wrow < 8)  ? (q_w + wrow * 64 + k)
                      : (wrow < 16) ? (k_w + (wrow - 8) * 64 + k)
                                    : (v_w + (wrow - 16) * 64 + k);
      float4 w0 = *(const float4*)wp;
      float4 w1 = *(const float4*)(wp + 4);
      u16x8 pk;
      pk[0] = f2b16(w0.x); pk[1] = f2b16(w0.y);
      pk[2] = f2b16(w0.z); pk[3] = f2b16(w0.w);
      pk[4] = f2b16(w1.x); pk[5] = f2b16(w1.y);
      pk[6] = f2b16(w1.z); pk[7] = f2b16(w1.w);
      bf16x8 bfv = *(const bf16x8*)(&clds[ns * 16 + l15][k]);
      a2 = __builtin_amdgcn_mfma_f32_16x16x32_bf16(
          __builtin_bit_cast(bf16x8, pk), bfv, a2, 0, 0, 0);
    }
    int ngl = n0 + ns * 16 + l15;
    if (t5 == 0) {
      u16x4 pk;
      #pragma unroll
      for (int r = 0; r < 4; ++r) {
        int row = lg * 4 + r;
        float bq = (row < 8) ? q_b[row] : k_b[row - 8];
        pk[r] = f2b16(a2[r] + bq);
      }
      if (lg < 2)
        *(u16x4*)(Qb + (((size_t)b << 12) + ngl) * 8 + lg * 4) = pk;
      else
        *(u16x4*)(Kb + (((size_t)b << 12) + ngl) * 8 + (lg - 2) * 4) = pk;
    } else {
      #pragma unroll
      for (int r = 0; r < 4; ++r) {
        int vch = (t5 - 1) * 16 + lg * 4 + r;
        vstage[vch][ns * 16 + l15] = f2b16(a2[r] + v_b[vch]);
      }
    }
  }
  __syncthreads();

  // ---- coalesced V store: 64ch x 32n ----
  #pragma unroll
  for (int i = 0; i < 2; ++i) {
    int idx = t + 256 * i;           // 0..511
    int row = idx >> 3, seg = idx & 7;
    u16x4 pv = *(const u16x4*)(&vstage[row][seg * 4]);
    *(u16x4*)(Vb + ((size_t)(b * 64 + row)) * 4096 + n0 + seg * 4) = pv;
  }
}

// ===========================================================================
// attn_fused: flash attention over one KV chunk of 512 (2048 blocks);
// last block per (b,q-tile) merges all 8 partials + fused epilogue.
__global__ __launch_bounds__(256) void attn_fused_kernel(
    const unsigned short* __restrict__ Qb, const unsigned short* __restrict__ Kb,
    const unsigned short* __restrict__ Vb, const unsigned short* __restrict__ cb,
    const float* __restrict__ xin,
    const float* __restrict__ psi_w, const float* __restrict__ psi_b,
    const float* __restrict__ bnp_w, const float* __restrict__ bnp_b,
    const float* __restrict__ bnp_m, const float* __restrict__ bnp_v,
    const float* __restrict__ sa_gamma,
    unsigned short* __restrict__ Opart, float* __restrict__ ml,
    int* __restrict__ cnt, float* __restrict__ out)
{
  __shared__ __attribute__((aligned(16))) char smem[19456];
  __shared__ int is_last;
  // main-loop aliases
  auto klds = (unsigned short(*)[8])smem;                    // 64*8*2    = 1024
  auto vlds = (unsigned short(*)[72])(smem + 1024);          // 64*72*2   = 9216
  auto plds = (unsigned short(*)[16][72])(smem + 10240);     // 4*16*72*2 = 9216
  // combine-phase aliases (used after full-block barrier)
  auto ml_lds = (float2(*)[8])smem;                          // 64*8*8 = 4096
  float* psi_lds = (float*)(smem + 4096);                    // 64*4

  const int t = threadIdx.x;
  const int bid = blockIdx.x;
  const int qt = bid & 63;
  const int b = (bid >> 6) & 3;
  const int ci = bid >> 8;            // KV chunk 0..7
  const int n0 = qt << 6;
  const int l = t & 63, w = t >> 6;
  const int l15 = l & 15, lg = l >> 4;

  bf16x8 qf = {0, 0, 0, 0, 0, 0, 0, 0};
  if (lg == 0)
    qf = *(const bf16x8*)(Qb + (((size_t)b << 12) + n0 + w * 16 + l15) * 8);

  f32x4 zf = {0.f, 0.f, 0.f, 0.f};
  f32x4 O[4];
  O[0] = O[1] = O[2] = O[3] = zf;
  float m_run[4] = {-INFINITY, -INFINITY, -INFINITY, -INFINITY};
  float l_run[4] = {0.f, 0.f, 0.f, 0.f};

  const int m_lo = ci << 9, m_hi = (ci + 1) << 9;
  for (int m0 = m_lo; m0 < m_hi; m0 += 64) {
    if (t < 64)
      *(int4*)(&klds[t][0]) = *(const int4*)(Kb + (((size_t)b << 12) + m0 + t) * 8);
    #pragma unroll
    for (int i = 0; i < 2; ++i) {
      int ci2 = t + 256 * i;
      int row = ci2 >> 3, off = ci2 & 7;
      *(int4*)(&vlds[row][off * 8]) =
          *(const int4*)(Vb + ((size_t)(b * 64 + row)) * 4096 + m0 + off * 8);
    }
    __syncthreads();

    f32x4 e[4];
    #pragma unroll
    for (int mt = 0; mt < 4; ++mt) {
      bf16x8 kf = *(const bf16x8*)(&klds[mt * 16 + l15][0]);
      e[mt] = __builtin_amdgcn_mfma_f32_16x16x32_bf16(qf, kf, zf, 0, 0, 0);
    }

    #pragma unroll
    for (int r = 0; r < 4; ++r) {
      float vm = fmaxf(fmaxf(e[0][r], e[1][r]), fmaxf(e[2][r], e[3][r]));
      vm = fmaxf(vm, __shfl_xor(vm, 1));
      vm = fmaxf(vm, __shfl_xor(vm, 2));
      vm = fmaxf(vm, __shfl_xor(vm, 4));
      vm = fmaxf(vm, __shfl_xor(vm, 8));
      float nm = fmaxf(m_run[r], vm);
      float sc = __expf(m_run[r] - nm);
      float s = 0.f;
      #pragma unroll
      for (int mt = 0; mt < 4; ++mt) {
        float p = __expf(e[mt][r] - nm);
        e[mt][r] = p;
        s += p;
      }
      s += __shfl_xor(s, 1);
      s += __shfl_xor(s, 2);
      s += __shfl_xor(s, 4);
      s += __shfl_xor(s, 8);
      l_run[r] = l_run[r] * sc + s;
      m_run[r] = nm;
      #pragma unroll
      for (int mt = 0; mt < 4; ++mt)
        plds[w][lg * 4 + r][mt * 16 + l15] = f2b16(e[mt][r]);
      #pragma unroll
      for (int ct = 0; ct < 4; ++ct) O[ct][r] *= sc;
    }

    #pragma unroll
    for (int ct = 0; ct < 4; ++ct) {
      #pragma unroll
      for (int kk = 0; kk < 2; ++kk) {
        bf16x8 pa = *(const bf16x8*)(&plds[w][l15][kk * 32 + lg * 8]);
        bf16x8 vb = *(const bf16x8*)(&vlds[ct * 16 + l15][kk * 32 + lg * 8]);
        O[ct] = __builtin_amdgcn_mfma_f32_16x16x32_bf16(pa, vb, O[ct], 0, 0, 0);
      }
    }
    __syncthreads();
  }

  // ---- store partials (bf16 O, f32 m/l) ----
  const size_t pb = ((size_t)(ci * 4 + b)) << 12;
  #pragma unroll
  for (int ct = 0; ct < 4; ++ct) {
    int ch = ct * 16 + l15;
    #pragma unroll
    for (int r = 0; r < 4; ++r) {
      int qg = n0 + w * 16 + lg * 4 + r;
      Opart[(pb + qg) * 64 + ch] = f2b16(O[ct][r]);
    }
  }
  if (l15 == 0) {
    #pragma unroll
    for (int r = 0; r < 4; ++r) {
      int qg = n0 + w * 16 + lg * 4 + r;
      float2 mv;
      mv.x = m_run[r]; mv.y = l_run[r];
      *(float2*)(ml + (pb + qg) * 2) = mv;
    }
  }

  // ---- split-K completion protocol ----
  __threadfence();
  __syncthreads();
  if (t == 0)
    is_last = (atomicAdd(&cnt[b * 64 + qt], 1) == 7);
  __syncthreads();
  if (!is_last) return;
  __threadfence();   // acquire: other blocks' partials now visible

  // ---- combine phase (this block only): 64 q x 64 ch ----
  #pragma unroll
  for (int i = 0; i < 2; ++i) {
    int idx = t + 256 * i;           // 0..511 = 8ci x 64q
    int cj = idx >> 6, q = idx & 63;
    ml_lds[q][cj] = *(const float2*)(ml + ((((size_t)(cj * 4 + b)) << 12) + n0 + q) * 2);
  }
  __syncthreads();

  const float invp = bnp_w[0] * rsqrtf(bnp_v[0] + EPSV);
  const float psi_c = (psi_b[0] - bnp_m[0]) * invp + bnp_b[0];
  const float gamma = sa_gamma[0];

  const int q = t >> 2, cg = t & 3;   // 64 q x 4 ch-groups of 16
  const int qg = n0 + q;

  float M = -INFINITY;
  #pragma unroll
  for (int cj = 0; cj < 8; ++cj) M = fmaxf(M, ml_lds[q][cj].x);
  float L = 0.f, wgt[8];
  #pragma unroll
  for (int cj = 0; cj < 8; ++cj) {
    wgt[cj] = __expf(ml_lds[q][cj].x - M);
    L += wgt[cj] * ml_lds[q][cj].y;
  }
  float osum[16];
  #pragma unroll
  for (int k = 0; k < 16; ++k) osum[k] = 0.f;
  #pragma unroll
  for (int cj = 0; cj < 8; ++cj) {
    const unsigned short* base =
        Opart + ((((size_t)(cj * 4 + b)) << 12) + qg) * 64 + cg * 16;
    float wv = wgt[cj];
    #pragma unroll
    for (int s4 = 0; s4 < 4; ++s4) {
      u16x4 p = *(const u16x4*)(base + s4 * 4);
      #pragma unroll
      for (int j = 0; j < 4; ++j) osum[s4 * 4 + j] += wv * b2f(p[j]);
    }
  }
  const float invL = 1.f / L;
  float ps = 0.f;
  #pragma unroll
  for (int k = 0; k < 16; ++k) {
    int ch = cg * 16 + k;
    float cv = b2f(cb[((size_t)(b * 64 + ch)) * 4096 + qg]);
    ps += (psi_w[ch] * invp) * (gamma * (osum[k] * invL) + cv);
  }
  ps += __shfl_xor(ps, 1);
  ps += __shfl_xor(ps, 2);
  if (cg == 0)
    psi_lds[q] = 1.f / (1.f + __expf(-(ps + psi_c)));
  __syncthreads();

  // ---- out = x * psi (128 ch x 64 n) ----
  #pragma unroll
  for (int i = 0; i < 8; ++i) {
    int idx = t + 256 * i;           // 0..2047
    int f = idx >> 4, c4 = idx & 15;
    size_t off = ((size_t)(b * 128 + f)) * 4096 + n0 + c4 * 4;
    float4 xv = *(const float4*)(xin + off);
    float4 ov;
    ov.x = xv.x * psi_lds[c4 * 4 + 0];
    ov.y = xv.y * psi_lds[c4 * 4 + 1];
    ov.z = xv.z * psi_lds[c4 * 4 + 2];
    ov.w = xv.w * psi_lds[c4 * 4 + 3];
    *(float4*)(out + off) = ov;
  }
}

// ===========================================================================
extern "C" void kernel_launch(void* const* d_in, const int* in_sizes, int n_in,
                              void* d_out, int out_size, void* d_ws, size_t ws_size,
                              hipStream_t stream) {
  (void)in_sizes; (void)n_in; (void)out_size; (void)ws_size;
  const float* g     = (const float*)d_in[0];
  const float* x     = (const float*)d_in[1];
  const float* wg_w  = (const float*)d_in[2];
  const float* wg_b  = (const float*)d_in[3];
  const float* bng_w = (const float*)d_in[4];
  const float* bng_b = (const float*)d_in[5];
  const float* bng_m = (const float*)d_in[6];
  const float* bng_v = (const float*)d_in[7];
  const float* wx_w  = (const float*)d_in[8];
  const float* wx_b  = (const float*)d_in[9];
  const float* bnx_w = (const float*)d_in[10];
  const float* bnx_b = (const float*)d_in[11];
  const float* bnx_m = (const float*)d_in[12];
  const float* bnx_v = (const float*)d_in[13];
  const float* q_w   = (const float*)d_in[14];
  const float* q_b   = (const float*)d_in[15];
  const float* k_w   = (const float*)d_in[16];
  const float* k_b   = (const float*)d_in[17];
  const float* v_w   = (const float*)d_in[18];
  const float* v_b   = (const float*)d_in[19];
  const float* sa_g  = (const float*)d_in[20];
  const float* psi_w = (const float*)d_in[21];
  const float* psi_b = (const float*)d_in[22];
  const float* bnp_w = (const float*)d_in[23];
  const float* bnp_b = (const float*)d_in[24];
  const float* bnp_m = (const float*)d_in[25];
  const float* bnp_v = (const float*)d_in[26];
  float* out = (float*)d_out;

  char* ws = (char*)d_ws;
  unsigned short* cb = (unsigned short*)(ws + C_OFF);
  unsigned short* Qb = (unsigned short*)(ws + Q_OFF);
  unsigned short* Kb = (unsigned short*)(ws + K_OFF);
  unsigned short* Vb = (unsigned short*)(ws + V_OFF);
  unsigned short* Opart = (unsigned short*)(ws + OPART_OFF);
  float* mlb = (float*)(ws + ML_OFF);
  int* cnt   = (int*)(ws + CNT_OFF);

  hipLaunchKernelGGL(conv_fused_kernel, dim3(512), dim3(256), 0, stream,
                     g, x, wg_w, wg_b, bng_w, bng_b, bng_m, bng_v,
                     wx_w, wx_b, bnx_w, bnx_b, bnx_m, bnx_v,
                     q_w, q_b, k_w, k_b, v_w, v_b,
                     cb, Qb, Kb, Vb, cnt);

  hipLaunchKernelGGL(attn_fused_kernel, dim3(2048), dim3(256), 0, stream,
                     Qb, Kb, Vb, cb, x,
                     psi_w, psi_b, bnp_w, bnp_b, bnp_m, bnp_v, sa_g,
                     Opart, mlb, cnt, out);
}

// Round 5
// 193.545 us; speedup vs baseline: 2.1692x; 2.1692x over previous
//
#include <hip/hip_runtime.h>
#include <hip/hip_bf16.h>

// ---------------------------------------------------------------------------
// AttentionBlockWithSelfAttention on MI355X (gfx950)
// B=4, Cin=128, Fi=64, H=W=64, N=4096, d_qk=8
//
// THREE dispatches (r4 lesson: device-scope fences in-kernel = L2 writeback
// stall per block -> 5x regression; cross-block reduction stays a dispatch):
//   k1 conv_fused: BN folded per-lane; c=relu(conv), Q(x log2e)/K/V bf16
//   k2 attn_part:  flash attention, KV split x8, exp2-domain softmax,
//                  T13 defer-rescale -> partial O(bf16), m,l
//   k3 combine:    merge 8 partials (exp2 weights) + psi/sigmoid + x*psi
// ---------------------------------------------------------------------------

typedef short bf16x8 __attribute__((ext_vector_type(8)));
typedef unsigned short u16x8 __attribute__((ext_vector_type(8)));
typedef unsigned short u16x4 __attribute__((ext_vector_type(4)));
typedef float f32x4 __attribute__((ext_vector_type(4)));

__device__ __forceinline__ unsigned short f2b16(float f) {
  return __builtin_bit_cast(unsigned short, __float2bfloat16(f));
}
__device__ __forceinline__ float b2f(unsigned short u) {
  return __bfloat162float(__builtin_bit_cast(__hip_bfloat16, u));
}

#define EPSV 1e-5f
#define LOG2E 1.44269504088896340736f

// ---- workspace layout (bytes) ----
#define C_OFF      0u                      // 4*64*4096 bf16 = 2097152
#define Q_OFF      (C_OFF + 2097152u)      // 4*4096*8 bf16 = 262144
#define K_OFF      (Q_OFF + 262144u)
#define V_OFF      (K_OFF + 262144u)       // 4*64*4096 bf16 = 2097152
#define OPART_OFF  (V_OFF + 2097152u)      // 32*4096*64 bf16 = 16777216
#define ML_OFF     (OPART_OFF + 16777216u) // 32*4096*2 f32 = 1048576

// ===========================================================================
// conv_fused: one block per (b, 16-point tile). 1024 blocks, 4 waves.
// BN folding done per-lane in registers (no prep kernel).
__global__ __launch_bounds__(256) void conv_fused_kernel(
    const float* __restrict__ g, const float* __restrict__ x,
    const float* __restrict__ wg_w, const float* __restrict__ wg_b,
    const float* __restrict__ bng_w, const float* __restrict__ bng_b,
    const float* __restrict__ bng_m, const float* __restrict__ bng_v,
    const float* __restrict__ wx_w, const float* __restrict__ wx_b,
    const float* __restrict__ bnx_w, const float* __restrict__ bnx_b,
    const float* __restrict__ bnx_m, const float* __restrict__ bnx_v,
    const float* __restrict__ q_w, const float* __restrict__ q_b,
    const float* __restrict__ k_w, const float* __restrict__ k_b,
    const float* __restrict__ v_w, const float* __restrict__ v_b,
    unsigned short* __restrict__ cb, unsigned short* __restrict__ Qb,
    unsigned short* __restrict__ Kb, unsigned short* __restrict__ Vb)
{
  __shared__ __attribute__((aligned(16))) unsigned short xt[16][264];    // [n][k]
  __shared__ __attribute__((aligned(16))) unsigned short clds[16][72];   // [n][o]
  __shared__ __attribute__((aligned(16))) unsigned short vstage[64][20]; // [ch][n]

  const int t = threadIdx.x;
  const int bid = blockIdx.x;
  const int b = bid >> 8;
  const int n0 = (bid & 255) << 4;

  // ---- stage [g;x] tile transposed to [n][k] bf16 ----
  {
    const int col4 = t & 3;          // n offset = col4*4
    const int rowg = t >> 2;         // rows rowg*4 .. +3
    float4 v[4];
    #pragma unroll
    for (int rr = 0; rr < 4; ++rr) {
      int row = rowg * 4 + rr;
      const float* src = (row < 128)
          ? (g + ((size_t)(b * 128 + row)) * 4096 + n0 + col4 * 4)
          : (x + ((size_t)(b * 128 + (row - 128))) * 4096 + n0 + col4 * 4);
      v[rr] = *(const float4*)src;
    }
    #pragma unroll
    for (int j = 0; j < 4; ++j) {
      u16x4 pk;
      #pragma unroll
      for (int rr = 0; rr < 4; ++rr)
        pk[rr] = f2b16(((const float*)&v[rr])[j]);
      *(u16x4*)(&xt[col4 * 4 + j][rowg * 4]) = pk;
    }
  }

  const int l = t & 63, w = t >> 6;
  const int l15 = l & 15, lg = l >> 4;
  f32x4 zf = {0.f, 0.f, 0.f, 0.f};

  // ---- per-lane BN-folded A-fragments for the conv GEMM ----
  const int orow = w * 16 + l15;
  const float invg = bng_w[orow] * rsqrtf(bng_v[orow] + EPSV);
  const float invx = bnx_w[orow] * rsqrtf(bnx_v[orow] + EPSV);
  bf16x8 afrag[8];
  #pragma unroll
  for (int ks = 0; ks < 8; ++ks) {
    int k = ks * 32 + lg * 8;        // 8-chunk never straddles k=128
    const float* wp;
    float sc;
    if (k < 128) { wp = wg_w + orow * 128 + k;         sc = invg; }
    else         { wp = wx_w + orow * 128 + (k - 128); sc = invx; }
    float4 w0 = *(const float4*)wp;
    float4 w1 = *(const float4*)(wp + 4);
    u16x8 pk;
    pk[0] = f2b16(w0.x * sc); pk[1] = f2b16(w0.y * sc);
    pk[2] = f2b16(w0.z * sc); pk[3] = f2b16(w0.w * sc);
    pk[4] = f2b16(w1.x * sc); pk[5] = f2b16(w1.y * sc);
    pk[6] = f2b16(w1.z * sc); pk[7] = f2b16(w1.w * sc);
    afrag[ks] = __builtin_bit_cast(bf16x8, pk);
  }
  __syncthreads();

  // ---- conv MFMA: wave w owns o-rows [16w,16w+16) ----
  f32x4 acc = zf;
  #pragma unroll
  for (int ks = 0; ks < 8; ++ks) {
    bf16x8 bfv = *(const bf16x8*)(&xt[l15][ks * 32 + lg * 8]);
    acc = __builtin_amdgcn_mfma_f32_16x16x32_bf16(afrag[ks], bfv, acc, 0, 0, 0);
  }
  #pragma unroll
  for (int r = 0; r < 4; ++r) {
    int o = w * 16 + lg * 4 + r;
    float ig = bng_w[o] * rsqrtf(bng_v[o] + EPSV);
    float ix = bnx_w[o] * rsqrtf(bnx_v[o] + EPSV);
    float bc = (wg_b[o] - bng_m[o]) * ig + bng_b[o]
             + (wx_b[o] - bnx_m[o]) * ix + bnx_b[o];
    float cv = fmaxf(acc[r] + bc, 0.f);
    unsigned short cv16 = f2b16(cv);
    cb[((size_t)(b * 64 + o)) * 4096 + n0 + l15] = cv16;
    clds[l15][o] = cv16;
  }
  __syncthreads();

  // ---- QKV: 5 row-tiles of Wqkv over 4 waves (wave0 takes t5=0,4) ----
  const int ngl = n0 + l15;
  #pragma unroll
  for (int i = 0; i < 2; ++i) {
    int t5 = w + 4 * i;
    if (t5 >= 5) break;
    int wrow = t5 * 16 + l15;
    f32x4 a2 = zf;
    #pragma unroll
    for (int kk = 0; kk < 2; ++kk) {
      int k = kk * 32 + lg * 8;
      const float* wp = (wrow < 8)  ? (q_w + wrow * 64 + k)
                      : (wrow < 16) ? (k_w + (wrow - 8) * 64 + k)
                                    : (v_w + (wrow - 16) * 64 + k);
      float4 w0 = *(const float4*)wp;
      float4 w1 = *(const float4*)(wp + 4);
      u16x8 pk;
      pk[0] = f2b16(w0.x); pk[1] = f2b16(w0.y);
      pk[2] = f2b16(w0.z); pk[3] = f2b16(w0.w);
      pk[4] = f2b16(w1.x); pk[5] = f2b16(w1.y);
      pk[6] = f2b16(w1.z); pk[7] = f2b16(w1.w);
      bf16x8 bfv = *(const bf16x8*)(&clds[l15][k]);
      a2 = __builtin_amdgcn_mfma_f32_16x16x32_bf16(
          __builtin_bit_cast(bf16x8, pk), bfv, a2, 0, 0, 0);
    }
    if (t5 == 0) {
      // rows lg*4..+3: lg0/1 -> Q (scaled by log2e), lg2/3 -> K
      u16x4 pk;
      #pragma unroll
      for (int r = 0; r < 4; ++r) {
        int row = lg * 4 + r;
        float val;
        if (row < 8) val = (a2[r] + q_b[row]) * LOG2E;   // exp2-domain Q
        else         val = a2[r] + k_b[row - 8];
        pk[r] = f2b16(val);
      }
      if (lg < 2)
        *(u16x4*)(Qb + (((size_t)b << 12) + ngl) * 8 + lg * 4) = pk;
      else
        *(u16x4*)(Kb + (((size_t)b << 12) + ngl) * 8 + (lg - 2) * 4) = pk;
    } else {
      #pragma unroll
      for (int r = 0; r < 4; ++r) {
        int vch = (t5 - 1) * 16 + lg * 4 + r;
        vstage[vch][l15] = f2b16(a2[r] + v_b[vch]);
      }
    }
  }
  __syncthreads();

  // ---- coalesced V store: 64ch x 16n ----
  {
    int row = t >> 2, seg = t & 3;
    u16x4 pv = *(const u16x4*)(&vstage[row][seg * 4]);
    *(u16x4*)(Vb + ((size_t)(b * 64 + row)) * 4096 + n0 + seg * 4) = pv;
  }
}

// ===========================================================================
// attn_partial: flash attention over one KV chunk of 512. 2048 blocks.
// Softmax in exp2 domain (Q pre-scaled by log2e); T13 defer-rescale THR=8.
__global__ __launch_bounds__(256) void attn_partial_kernel(
    const unsigned short* __restrict__ Qb, const unsigned short* __restrict__ Kb,
    const unsigned short* __restrict__ Vb,
    unsigned short* __restrict__ Opart, float* __restrict__ ml)
{
  __shared__ __attribute__((aligned(16))) unsigned short klds[64][8];
  __shared__ __attribute__((aligned(16))) unsigned short vlds[64][72];
  __shared__ __attribute__((aligned(16))) unsigned short plds[4][16][72];

  const int t = threadIdx.x;
  const int bid = blockIdx.x;
  const int qt = bid & 63;
  const int b = (bid >> 6) & 3;
  const int ci = bid >> 8;            // KV chunk 0..7 (512 each)
  const int n0 = qt << 6;
  const int l = t & 63, w = t >> 6;
  const int l15 = l & 15, lg = l >> 4;

  bf16x8 qf = {0, 0, 0, 0, 0, 0, 0, 0};
  if (lg == 0)
    qf = *(const bf16x8*)(Qb + (((size_t)b << 12) + n0 + w * 16 + l15) * 8);

  f32x4 zf = {0.f, 0.f, 0.f, 0.f};
  f32x4 O[4];
  O[0] = O[1] = O[2] = O[3] = zf;
  float m_run[4] = {-INFINITY, -INFINITY, -INFINITY, -INFINITY};
  float l_run[4] = {0.f, 0.f, 0.f, 0.f};

  const int m_lo = ci << 9, m_hi = (ci + 1) << 9;
  for (int m0 = m_lo; m0 < m_hi; m0 += 64) {
    if (t < 64)
      *(int4*)(&klds[t][0]) = *(const int4*)(Kb + (((size_t)b << 12) + m0 + t) * 8);
    #pragma unroll
    for (int i = 0; i < 2; ++i) {
      int ci2 = t + 256 * i;
      int row = ci2 >> 3, off = ci2 & 7;
      *(int4*)(&vlds[row][off * 8]) =
          *(const int4*)(Vb + ((size_t)(b * 64 + row)) * 4096 + m0 + off * 8);
    }
    __syncthreads();

    f32x4 e[4];
    #pragma unroll
    for (int mt = 0; mt < 4; ++mt) {
      bf16x8 kf = *(const bf16x8*)(&klds[mt * 16 + l15][0]);
      e[mt] = __builtin_amdgcn_mfma_f32_16x16x32_bf16(qf, kf, zf, 0, 0, 0);
    }

    #pragma unroll
    for (int r = 0; r < 4; ++r) {
      float vm = fmaxf(fmaxf(e[0][r], e[1][r]), fmaxf(e[2][r], e[3][r]));
      vm = fmaxf(vm, __shfl_xor(vm, 1));
      vm = fmaxf(vm, __shfl_xor(vm, 2));
      vm = fmaxf(vm, __shfl_xor(vm, 4));
      vm = fmaxf(vm, __shfl_xor(vm, 8));
      // T13 defer-rescale: keep old max while growth <= 8 (P <= 2^8)
      bool nosk = !__all(vm <= m_run[r] + 8.f);
      float nm = nosk ? fmaxf(m_run[r], vm) : m_run[r];
      float s = 0.f;
      #pragma unroll
      for (int mt = 0; mt < 4; ++mt) {
        float p = __builtin_amdgcn_exp2f(e[mt][r] - nm);
        e[mt][r] = p;
        s += p;
      }
      s += __shfl_xor(s, 1);
      s += __shfl_xor(s, 2);
      s += __shfl_xor(s, 4);
      s += __shfl_xor(s, 8);
      if (nosk) {
        float sc = __builtin_amdgcn_exp2f(m_run[r] - nm);
        l_run[r] = l_run[r] * sc + s;
        m_run[r] = nm;
        #pragma unroll
        for (int ct = 0; ct < 4; ++ct) O[ct][r] *= sc;
      } else {
        l_run[r] += s;
      }
      #pragma unroll
      for (int mt = 0; mt < 4; ++mt)
        plds[w][lg * 4 + r][mt * 16 + l15] = f2b16(e[mt][r]);
    }

    #pragma unroll
    for (int ct = 0; ct < 4; ++ct) {
      #pragma unroll
      for (int kk = 0; kk < 2; ++kk) {
        bf16x8 pa = *(const bf16x8*)(&plds[w][l15][kk * 32 + lg * 8]);
        bf16x8 vb = *(const bf16x8*)(&vlds[ct * 16 + l15][kk * 32 + lg * 8]);
        O[ct] = __builtin_amdgcn_mfma_f32_16x16x32_bf16(pa, vb, O[ct], 0, 0, 0);
      }
    }
    __syncthreads();
  }

  // ---- store partials: O bf16 (unnormalized) + (m,l) f32 ----
  const size_t pb = ((size_t)(ci * 4 + b)) << 12;
  #pragma unroll
  for (int ct = 0; ct < 4; ++ct) {
    int ch = ct * 16 + l15;
    #pragma unroll
    for (int r = 0; r < 4; ++r) {
      int qg = n0 + w * 16 + lg * 4 + r;
      Opart[(pb + qg) * 64 + ch] = f2b16(O[ct][r]);
    }
  }
  if (l15 == 0) {
    #pragma unroll
    for (int r = 0; r < 4; ++r) {
      int qg = n0 + w * 16 + lg * 4 + r;
      float2 mv;
      mv.x = m_run[r]; mv.y = l_run[r];
      *(float2*)(ml + (pb + qg) * 2) = mv;
    }
  }
}

// ===========================================================================
// combine: merge 8 KV-chunk partials + fused epilogue. 1024 blocks, 16 q each.
__global__ __launch_bounds__(256) void combine_kernel(
    const unsigned short* __restrict__ Opart, const float* __restrict__ ml,
    const unsigned short* __restrict__ cb, const float* __restrict__ xin,
    const float* __restrict__ psi_w, const float* __restrict__ psi_b,
    const float* __restrict__ bnp_w, const float* __restrict__ bnp_b,
    const float* __restrict__ bnp_m, const float* __restrict__ bnp_v,
    const float* __restrict__ sa_gamma,
    float* __restrict__ out)
{
  __shared__ __attribute__((aligned(16))) unsigned short c_lds[64][20]; // [ch][n]
  __shared__ __attribute__((aligned(8))) float2 ml_lds[16][8];
  __shared__ float psi_lds[16];

  const int t = threadIdx.x;
  const int bid = blockIdx.x;
  const int b = bid >> 8;
  const int n0 = (bid & 255) << 4;

  // stage c tile [64ch][16n] bf16
  {
    int row = t >> 2, seg = t & 3;
    *(u16x4*)(&c_lds[row][seg * 4]) =
        *(const u16x4*)(cb + ((size_t)(b * 64 + row)) * 4096 + n0 + seg * 4);
  }
  // stage ml [16q][8ci]
  if (t < 128) {
    int q = t >> 3, ci = t & 7;
    ml_lds[q][ci] = *(const float2*)(ml + ((((size_t)(ci * 4 + b)) << 12) + n0 + q) * 2);
  }
  __syncthreads();

  const float invp = bnp_w[0] * rsqrtf(bnp_v[0] + EPSV);
  const float psi_c = (psi_b[0] - bnp_m[0]) * invp + bnp_b[0];
  const float gamma = sa_gamma[0];

  const int q = t >> 4, cg = t & 15;
  const int qg = n0 + q;

  float M = -INFINITY;
  #pragma unroll
  for (int ci = 0; ci < 8; ++ci) M = fmaxf(M, ml_lds[q][ci].x);
  float L = 0.f, wgt[8];
  #pragma unroll
  for (int ci = 0; ci < 8; ++ci) {
    wgt[ci] = __builtin_amdgcn_exp2f(ml_lds[q][ci].x - M);  // exp2-domain m
    L += wgt[ci] * ml_lds[q][ci].y;
  }
  float o4[4] = {0.f, 0.f, 0.f, 0.f};
  #pragma unroll
  for (int ci = 0; ci < 8; ++ci) {
    u16x4 p = *(const u16x4*)(Opart + ((((size_t)(ci * 4 + b)) << 12) + qg) * 64 + cg * 4);
    float wv = wgt[ci];
    #pragma unroll
    for (int k = 0; k < 4; ++k) o4[k] += wv * b2f(p[k]);
  }
  const float invL = 1.f / L;
  float ps = 0.f;
  #pragma unroll
  for (int k = 0; k < 4; ++k) {
    int ch = cg * 4 + k;
    ps += (psi_w[ch] * invp) * (gamma * (o4[k] * invL) + b2f(c_lds[ch][q]));
  }
  ps += __shfl_xor(ps, 1);
  ps += __shfl_xor(ps, 2);
  ps += __shfl_xor(ps, 4);
  ps += __shfl_xor(ps, 8);
  if (cg == 0)
    psi_lds[q] = 1.f / (1.f + __expf(-(ps + psi_c)));
  __syncthreads();

  // out = x * psi : 128f x 16n
  #pragma unroll
  for (int i = 0; i < 2; ++i) {
    int idx = t + 256 * i;
    int f = idx >> 2, c4 = idx & 3;
    size_t off = ((size_t)(b * 128 + f)) * 4096 + n0 + c4 * 4;
    float4 xv = *(const float4*)(xin + off);
    float4 ov;
    ov.x = xv.x * psi_lds[c4 * 4 + 0];
    ov.y = xv.y * psi_lds[c4 * 4 + 1];
    ov.z = xv.z * psi_lds[c4 * 4 + 2];
    ov.w = xv.w * psi_lds[c4 * 4 + 3];
    *(float4*)(out + off) = ov;
  }
}

// ===========================================================================
extern "C" void kernel_launch(void* const* d_in, const int* in_sizes, int n_in,
                              void* d_out, int out_size, void* d_ws, size_t ws_size,
                              hipStream_t stream) {
  (void)in_sizes; (void)n_in; (void)out_size; (void)ws_size;
  const float* g     = (const float*)d_in[0];
  const float* x     = (const float*)d_in[1];
  const float* wg_w  = (const float*)d_in[2];
  const float* wg_b  = (const float*)d_in[3];
  const float* bng_w = (const float*)d_in[4];
  const float* bng_b = (const float*)d_in[5];
  const float* bng_m = (const float*)d_in[6];
  const float* bng_v = (const float*)d_in[7];
  const float* wx_w  = (const float*)d_in[8];
  const float* wx_b  = (const float*)d_in[9];
  const float* bnx_w = (const float*)d_in[10];
  const float* bnx_b = (const float*)d_in[11];
  const float* bnx_m = (const float*)d_in[12];
  const float* bnx_v = (const float*)d_in[13];
  const float* q_w   = (const float*)d_in[14];
  const float* q_b   = (const float*)d_in[15];
  const float* k_w   = (const float*)d_in[16];
  const float* k_b   = (const float*)d_in[17];
  const float* v_w   = (const float*)d_in[18];
  const float* v_b   = (const float*)d_in[19];
  const float* sa_g  = (const float*)d_in[20];
  const float* psi_w = (const float*)d_in[21];
  const float* psi_b = (const float*)d_in[22];
  const float* bnp_w = (const float*)d_in[23];
  const float* bnp_b = (const float*)d_in[24];
  const float* bnp_m = (const float*)d_in[25];
  const float* bnp_v = (const float*)d_in[26];
  float* out = (float*)d_out;

  char* ws = (char*)d_ws;
  unsigned short* cb = (unsigned short*)(ws + C_OFF);
  unsigned short* Qb = (unsigned short*)(ws + Q_OFF);
  unsigned short* Kb = (unsigned short*)(ws + K_OFF);
  unsigned short* Vb = (unsigned short*)(ws + V_OFF);
  unsigned short* Opart = (unsigned short*)(ws + OPART_OFF);
  float* mlb = (float*)(ws + ML_OFF);

  hipLaunchKernelGGL(conv_fused_kernel, dim3(1024), dim3(256), 0, stream,
                     g, x, wg_w, wg_b, bng_w, bng_b, bng_m, bng_v,
                     wx_w, wx_b, bnx_w, bnx_b, bnx_m, bnx_v,
                     q_w, q_b, k_w, k_b, v_w, v_b,
                     cb, Qb, Kb, Vb);

  hipLaunchKernelGGL(attn_partial_kernel, dim3(2048), dim3(256), 0, stream,
                     Qb, Kb, Vb, Opart, mlb);

  hipLaunchKernelGGL(combine_kernel, dim3(1024), dim3(256), 0, stream,
                     Opart, mlb, cb, x,
                     psi_w, psi_b, bnp_w, bnp_b, bnp_m, bnp_v, sa_g,
                     out);
}

// Round 6
// 172.916 us; speedup vs baseline: 2.4280x; 1.1193x over previous
//
#include <hip/hip_runtime.h>
#include <hip/hip_bf16.h>

// ---------------------------------------------------------------------------
// AttentionBlockWithSelfAttention on MI355X (gfx950)
// B=4, Cin=128, Fi=64, H=W=64, N=4096, d_qk=8
//
// THREE dispatches:
//   k1 conv_fused: BN folded per-lane; c=relu(conv), Q(x log2e)/K/V bf16
//   k2 attn_part:  flash attention, KV split x8, SWAPPED-OPERAND softmax:
//                  e=mfma(K,Q) puts all kv of one q in-lane -> 2 shuffles
//                  instead of 32; P written in B-frag layout (4 ds_write_b64);
//                  O^T=mfma(V,P) so rescale uses scalar m_run. T13 defer-max.
//   k3 combine:    merge 8 partials (exp2 weights) + psi/sigmoid + x*psi
// ---------------------------------------------------------------------------

typedef short bf16x8 __attribute__((ext_vector_type(8)));
typedef unsigned short u16x8 __attribute__((ext_vector_type(8)));
typedef unsigned short u16x4 __attribute__((ext_vector_type(4)));
typedef float f32x4 __attribute__((ext_vector_type(4)));

__device__ __forceinline__ unsigned short f2b16(float f) {
  return __builtin_bit_cast(unsigned short, __float2bfloat16(f));
}
__device__ __forceinline__ float b2f(unsigned short u) {
  return __bfloat162float(__builtin_bit_cast(__hip_bfloat16, u));
}

#define EPSV 1e-5f
#define LOG2E 1.44269504088896340736f

// ---- workspace layout (bytes) ----
#define C_OFF      0u                      // 4*64*4096 bf16 = 2097152
#define Q_OFF      (C_OFF + 2097152u)      // 4*4096*8 bf16 = 262144
#define K_OFF      (Q_OFF + 262144u)
#define V_OFF      (K_OFF + 262144u)       // 4*64*4096 bf16 = 2097152
#define OPART_OFF  (V_OFF + 2097152u)      // 32*4096*64 bf16 = 16777216
#define ML_OFF     (OPART_OFF + 16777216u) // 32*4096*2 f32 = 1048576

// ===========================================================================
// conv_fused: one block per (b, 16-point tile). 1024 blocks, 4 waves.
__global__ __launch_bounds__(256) void conv_fused_kernel(
    const float* __restrict__ g, const float* __restrict__ x,
    const float* __restrict__ wg_w, const float* __restrict__ wg_b,
    const float* __restrict__ bng_w, const float* __restrict__ bng_b,
    const float* __restrict__ bng_m, const float* __restrict__ bng_v,
    const float* __restrict__ wx_w, const float* __restrict__ wx_b,
    const float* __restrict__ bnx_w, const float* __restrict__ bnx_b,
    const float* __restrict__ bnx_m, const float* __restrict__ bnx_v,
    const float* __restrict__ q_w, const float* __restrict__ q_b,
    const float* __restrict__ k_w, const float* __restrict__ k_b,
    const float* __restrict__ v_w, const float* __restrict__ v_b,
    unsigned short* __restrict__ cb, unsigned short* __restrict__ Qb,
    unsigned short* __restrict__ Kb, unsigned short* __restrict__ Vb)
{
  __shared__ __attribute__((aligned(16))) unsigned short xt[16][264];    // [n][k]
  __shared__ __attribute__((aligned(16))) unsigned short clds[16][72];   // [n][o]
  __shared__ __attribute__((aligned(16))) unsigned short vstage[64][20]; // [ch][n]

  const int t = threadIdx.x;
  const int bid = blockIdx.x;
  const int b = bid >> 8;
  const int n0 = (bid & 255) << 4;

  // ---- stage [g;x] tile transposed to [n][k] bf16 ----
  {
    const int col4 = t & 3;
    const int rowg = t >> 2;
    float4 v[4];
    #pragma unroll
    for (int rr = 0; rr < 4; ++rr) {
      int row = rowg * 4 + rr;
      const float* src = (row < 128)
          ? (g + ((size_t)(b * 128 + row)) * 4096 + n0 + col4 * 4)
          : (x + ((size_t)(b * 128 + (row - 128))) * 4096 + n0 + col4 * 4);
      v[rr] = *(const float4*)src;
    }
    #pragma unroll
    for (int j = 0; j < 4; ++j) {
      u16x4 pk;
      #pragma unroll
      for (int rr = 0; rr < 4; ++rr)
        pk[rr] = f2b16(((const float*)&v[rr])[j]);
      *(u16x4*)(&xt[col4 * 4 + j][rowg * 4]) = pk;
    }
  }

  const int l = t & 63, w = t >> 6;
  const int l15 = l & 15, lg = l >> 4;
  f32x4 zf = {0.f, 0.f, 0.f, 0.f};

  // ---- per-lane BN-folded A-fragments ----
  const int orow = w * 16 + l15;
  const float invg = bng_w[orow] * rsqrtf(bng_v[orow] + EPSV);
  const float invx = bnx_w[orow] * rsqrtf(bnx_v[orow] + EPSV);
  bf16x8 afrag[8];
  #pragma unroll
  for (int ks = 0; ks < 8; ++ks) {
    int k = ks * 32 + lg * 8;
    const float* wp;
    float sc;
    if (k < 128) { wp = wg_w + orow * 128 + k;         sc = invg; }
    else         { wp = wx_w + orow * 128 + (k - 128); sc = invx; }
    float4 w0 = *(const float4*)wp;
    float4 w1 = *(const float4*)(wp + 4);
    u16x8 pk;
    pk[0] = f2b16(w0.x * sc); pk[1] = f2b16(w0.y * sc);
    pk[2] = f2b16(w0.z * sc); pk[3] = f2b16(w0.w * sc);
    pk[4] = f2b16(w1.x * sc); pk[5] = f2b16(w1.y * sc);
    pk[6] = f2b16(w1.z * sc); pk[7] = f2b16(w1.w * sc);
    afrag[ks] = __builtin_bit_cast(bf16x8, pk);
  }
  __syncthreads();

  // ---- conv MFMA ----
  f32x4 acc = zf;
  #pragma unroll
  for (int ks = 0; ks < 8; ++ks) {
    bf16x8 bfv = *(const bf16x8*)(&xt[l15][ks * 32 + lg * 8]);
    acc = __builtin_amdgcn_mfma_f32_16x16x32_bf16(afrag[ks], bfv, acc, 0, 0, 0);
  }
  #pragma unroll
  for (int r = 0; r < 4; ++r) {
    int o = w * 16 + lg * 4 + r;
    float ig = bng_w[o] * rsqrtf(bng_v[o] + EPSV);
    float ix = bnx_w[o] * rsqrtf(bnx_v[o] + EPSV);
    float bc = (wg_b[o] - bng_m[o]) * ig + bng_b[o]
             + (wx_b[o] - bnx_m[o]) * ix + bnx_b[o];
    float cv = fmaxf(acc[r] + bc, 0.f);
    unsigned short cv16 = f2b16(cv);
    cb[((size_t)(b * 64 + o)) * 4096 + n0 + l15] = cv16;
    clds[l15][o] = cv16;
  }
  __syncthreads();

  // ---- QKV: 5 row-tiles over 4 waves ----
  const int ngl = n0 + l15;
  #pragma unroll
  for (int i = 0; i < 2; ++i) {
    int t5 = w + 4 * i;
    if (t5 >= 5) break;
    int wrow = t5 * 16 + l15;
    f32x4 a2 = zf;
    #pragma unroll
    for (int kk = 0; kk < 2; ++kk) {
      int k = kk * 32 + lg * 8;
      const float* wp = (wrow < 8)  ? (q_w + wrow * 64 + k)
                      : (wrow < 16) ? (k_w + (wrow - 8) * 64 + k)
                                    : (v_w + (wrow - 16) * 64 + k);
      float4 w0 = *(const float4*)wp;
      float4 w1 = *(const float4*)(wp + 4);
      u16x8 pk;
      pk[0] = f2b16(w0.x); pk[1] = f2b16(w0.y);
      pk[2] = f2b16(w0.z); pk[3] = f2b16(w0.w);
      pk[4] = f2b16(w1.x); pk[5] = f2b16(w1.y);
      pk[6] = f2b16(w1.z); pk[7] = f2b16(w1.w);
      bf16x8 bfv = *(const bf16x8*)(&clds[l15][k]);
      a2 = __builtin_amdgcn_mfma_f32_16x16x32_bf16(
          __builtin_bit_cast(bf16x8, pk), bfv, a2, 0, 0, 0);
    }
    if (t5 == 0) {
      u16x4 pk;
      #pragma unroll
      for (int r = 0; r < 4; ++r) {
        int row = lg * 4 + r;
        float val;
        if (row < 8) val = (a2[r] + q_b[row]) * LOG2E;   // exp2-domain Q
        else         val = a2[r] + k_b[row - 8];
        pk[r] = f2b16(val);
      }
      if (lg < 2)
        *(u16x4*)(Qb + (((size_t)b << 12) + ngl) * 8 + lg * 4) = pk;
      else
        *(u16x4*)(Kb + (((size_t)b << 12) + ngl) * 8 + (lg - 2) * 4) = pk;
    } else {
      #pragma unroll
      for (int r = 0; r < 4; ++r) {
        int vch = (t5 - 1) * 16 + lg * 4 + r;
        vstage[vch][l15] = f2b16(a2[r] + v_b[vch]);
      }
    }
  }
  __syncthreads();

  // ---- coalesced V store ----
  {
    int row = t >> 2, seg = t & 3;
    u16x4 pv = *(const u16x4*)(&vstage[row][seg * 4]);
    *(u16x4*)(Vb + ((size_t)(b * 64 + row)) * 4096 + n0 + seg * 4) = pv;
  }
}

// ===========================================================================
// attn_partial: flash attention, KV chunk of 512. 2048 blocks.
// Swapped-operand MFMAs: e=mfma(K,Q) -> lane owns q=l15, kv in-lane;
// O^T=mfma(V,P) -> rescale by scalar m_run. exp2 domain, T13 defer-max.
__global__ __launch_bounds__(256) void attn_partial_kernel(
    const unsigned short* __restrict__ Qb, const unsigned short* __restrict__ Kb,
    const unsigned short* __restrict__ Vb,
    unsigned short* __restrict__ Opart, float* __restrict__ ml)
{
  __shared__ __attribute__((aligned(16))) unsigned short klds[64][8];
  __shared__ __attribute__((aligned(16))) unsigned short vlds[64][72];
  // P in B-fragment layout: [wave][kk][q=l15][4 lg-slots of 8 + 8 pad]
  // row stride 40 elems = 80 B (0 mod 16 -> b128-aligned; 20 dwords -> 2-way banks)
  __shared__ __attribute__((aligned(16))) unsigned short plds[4][2][16][40];

  const int t = threadIdx.x;
  const int bid = blockIdx.x;
  const int qt = bid & 63;
  const int b = (bid >> 6) & 3;
  const int ci = bid >> 8;            // KV chunk 0..7 (512 each)
  const int n0 = qt << 6;
  const int l = t & 63, w = t >> 6;
  const int l15 = l & 15, lg = l >> 4;

  bf16x8 qf = {0, 0, 0, 0, 0, 0, 0, 0};
  if (lg == 0)
    qf = *(const bf16x8*)(Qb + (((size_t)b << 12) + n0 + w * 16 + l15) * 8);

  f32x4 zf = {0.f, 0.f, 0.f, 0.f};
  f32x4 O[4];                         // O^T: lane ch=ct*16+lg*4+r, q=l15
  O[0] = O[1] = O[2] = O[3] = zf;
  float m_run = -INFINITY;            // per-lane scalars (q = l15)
  float l_run = 0.f;

  const int m_lo = ci << 9, m_hi = (ci + 1) << 9;
  for (int m0 = m_lo; m0 < m_hi; m0 += 64) {
    if (t < 64)
      *(int4*)(&klds[t][0]) = *(const int4*)(Kb + (((size_t)b << 12) + m0 + t) * 8);
    #pragma unroll
    for (int i = 0; i < 2; ++i) {
      int ci2 = t + 256 * i;
      int row = ci2 >> 3, off = ci2 & 7;
      *(int4*)(&vlds[row][off * 8]) =
          *(const int4*)(Vb + ((size_t)(b * 64 + row)) * 4096 + m0 + off * 8);
    }
    __syncthreads();

    // ---- energy (swapped): e[mt][r] = E[kv=mt*16+lg*4+r][q=l15] ----
    f32x4 e[4];
    #pragma unroll
    for (int mt = 0; mt < 4; ++mt) {
      bf16x8 kf = *(const bf16x8*)(&klds[mt * 16 + l15][0]);
      e[mt] = __builtin_amdgcn_mfma_f32_16x16x32_bf16(kf, qf, zf, 0, 0, 0);
    }

    // ---- in-register softmax for q = l15 ----
    float vm = fmaxf(fmaxf(fmaxf(e[0][0], e[0][1]), fmaxf(e[0][2], e[0][3])),
                     fmaxf(fmaxf(e[1][0], e[1][1]), fmaxf(e[1][2], e[1][3])));
    float vm2 = fmaxf(fmaxf(fmaxf(e[2][0], e[2][1]), fmaxf(e[2][2], e[2][3])),
                      fmaxf(fmaxf(e[3][0], e[3][1]), fmaxf(e[3][2], e[3][3])));
    vm = fmaxf(vm, vm2);
    vm = fmaxf(vm, __shfl_xor(vm, 16));
    vm = fmaxf(vm, __shfl_xor(vm, 32));

    bool nosk = __any(vm > m_run + 8.f);   // T13: rescale only on real growth
    float nm = nosk ? fmaxf(m_run, vm) : m_run;
    float s = 0.f;
    #pragma unroll
    for (int mt = 0; mt < 4; ++mt) {
      #pragma unroll
      for (int r = 0; r < 4; ++r) {
        float p = __builtin_amdgcn_exp2f(e[mt][r] - nm);
        e[mt][r] = p;
        s += p;
      }
    }
    s += __shfl_xor(s, 16);
    s += __shfl_xor(s, 32);
    if (nosk) {
      float sc = __builtin_amdgcn_exp2f(m_run - nm);
      l_run = l_run * sc + s;
      m_run = nm;
      #pragma unroll
      for (int ct = 0; ct < 4; ++ct)
        #pragma unroll
        for (int r = 0; r < 4; ++r) O[ct][r] *= sc;
    } else {
      l_run += s;
    }

    // ---- write P in B-fragment layout (4x ds_write_b64, per-wave buffer) ----
    #pragma unroll
    for (int mt = 0; mt < 4; ++mt) {
      u16x4 pk;
      #pragma unroll
      for (int r = 0; r < 4; ++r) pk[r] = f2b16(e[mt][r]);
      int kk = mt >> 1;
      int lgr = 2 * (mt & 1) + (lg >> 1);
      int j0 = 4 * (lg & 1);
      *(u16x4*)(&plds[w][kk][l15][lgr * 8 + j0]) = pk;
    }
    // same-wave RAW on plds: compiler inserts lgkmcnt; no barrier needed

    // ---- PV (swapped): O^T[ct] += V[ch][kv] . P[kv][q] ----
    #pragma unroll
    for (int ct = 0; ct < 4; ++ct) {
      #pragma unroll
      for (int kk = 0; kk < 2; ++kk) {
        bf16x8 pfr = *(const bf16x8*)(&plds[w][kk][l15][lg * 8]);
        bf16x8 vf = *(const bf16x8*)(&vlds[ct * 16 + l15][kk * 32 + lg * 8]);
        O[ct] = __builtin_amdgcn_mfma_f32_16x16x32_bf16(vf, pfr, O[ct], 0, 0, 0);
      }
    }
    __syncthreads();
  }

  // ---- store partials: O^T bf16 + (m,l) f32 ----
  const size_t pb = ((size_t)(ci * 4 + b)) << 12;
  const int qg = n0 + w * 16 + l15;
  #pragma unroll
  for (int ct = 0; ct < 4; ++ct) {
    u16x4 pk;
    #pragma unroll
    for (int r = 0; r < 4; ++r) pk[r] = f2b16(O[ct][r]);
    *(u16x4*)(Opart + (pb + qg) * 64 + ct * 16 + lg * 4) = pk;
  }
  if (lg == 0) {
    float2 mv;
    mv.x = m_run; mv.y = l_run;
    *(float2*)(ml + (pb + qg) * 2) = mv;
  }
}

// ===========================================================================
// combine: merge 8 KV-chunk partials + fused epilogue. 1024 blocks, 16 q each.
__global__ __launch_bounds__(256) void combine_kernel(
    const unsigned short* __restrict__ Opart, const float* __restrict__ ml,
    const unsigned short* __restrict__ cb, const float* __restrict__ xin,
    const float* __restrict__ psi_w, const float* __restrict__ psi_b,
    const float* __restrict__ bnp_w, const float* __restrict__ bnp_b,
    const float* __restrict__ bnp_m, const float* __restrict__ bnp_v,
    const float* __restrict__ sa_gamma,
    float* __restrict__ out)
{
  __shared__ __attribute__((aligned(16))) unsigned short c_lds[64][20];
  __shared__ __attribute__((aligned(8))) float2 ml_lds[16][8];
  __shared__ float psi_lds[16];

  const int t = threadIdx.x;
  const int bid = blockIdx.x;
  const int b = bid >> 8;
  const int n0 = (bid & 255) << 4;

  {
    int row = t >> 2, seg = t & 3;
    *(u16x4*)(&c_lds[row][seg * 4]) =
        *(const u16x4*)(cb + ((size_t)(b * 64 + row)) * 4096 + n0 + seg * 4);
  }
  if (t < 128) {
    int q = t >> 3, ci = t & 7;
    ml_lds[q][ci] = *(const float2*)(ml + ((((size_t)(ci * 4 + b)) << 12) + n0 + q) * 2);
  }
  __syncthreads();

  const float invp = bnp_w[0] * rsqrtf(bnp_v[0] + EPSV);
  const float psi_c = (psi_b[0] - bnp_m[0]) * invp + bnp_b[0];
  const float gamma = sa_gamma[0];

  const int q = t >> 4, cg = t & 15;
  const int qg = n0 + q;

  float M = -INFINITY;
  #pragma unroll
  for (int ci = 0; ci < 8; ++ci) M = fmaxf(M, ml_lds[q][ci].x);
  float L = 0.f, wgt[8];
  #pragma unroll
  for (int ci = 0; ci < 8; ++ci) {
    wgt[ci] = __builtin_amdgcn_exp2f(ml_lds[q][ci].x - M);
    L += wgt[ci] * ml_lds[q][ci].y;
  }
  float o4[4] = {0.f, 0.f, 0.f, 0.f};
  #pragma unroll
  for (int ci = 0; ci < 8; ++ci) {
    u16x4 p = *(const u16x4*)(Opart + ((((size_t)(ci * 4 + b)) << 12) + qg) * 64 + cg * 4);
    float wv = wgt[ci];
    #pragma unroll
    for (int k = 0; k < 4; ++k) o4[k] += wv * b2f(p[k]);
  }
  const float invL = 1.f / L;
  float ps = 0.f;
  #pragma unroll
  for (int k = 0; k < 4; ++k) {
    int ch = cg * 4 + k;
    ps += (psi_w[ch] * invp) * (gamma * (o4[k] * invL) + b2f(c_lds[ch][q]));
  }
  ps += __shfl_xor(ps, 1);
  ps += __shfl_xor(ps, 2);
  ps += __shfl_xor(ps, 4);
  ps += __shfl_xor(ps, 8);
  if (cg == 0)
    psi_lds[q] = 1.f / (1.f + __expf(-(ps + psi_c)));
  __syncthreads();

  #pragma unroll
  for (int i = 0; i < 2; ++i) {
    int idx = t + 256 * i;
    int f = idx >> 2, c4 = idx & 3;
    size_t off = ((size_t)(b * 128 + f)) * 4096 + n0 + c4 * 4;
    float4 xv = *(const float4*)(xin + off);
    float4 ov;
    ov.x = xv.x * psi_lds[c4 * 4 + 0];
    ov.y = xv.y * psi_lds[c4 * 4 + 1];
    ov.z = xv.z * psi_lds[c4 * 4 + 2];
    ov.w = xv.w * psi_lds[c4 * 4 + 3];
    *(float4*)(out + off) = ov;
  }
}

// ===========================================================================
extern "C" void kernel_launch(void* const* d_in, const int* in_sizes, int n_in,
                              void* d_out, int out_size, void* d_ws, size_t ws_size,
                              hipStream_t stream) {
  (void)in_sizes; (void)n_in; (void)out_size; (void)ws_size;
  const float* g     = (const float*)d_in[0];
  const float* x     = (const float*)d_in[1];
  const float* wg_w  = (const float*)d_in[2];
  const float* wg_b  = (const float*)d_in[3];
  const float* bng_w = (const float*)d_in[4];
  const float* bng_b = (const float*)d_in[5];
  const float* bng_m = (const float*)d_in[6];
  const float* bng_v = (const float*)d_in[7];
  const float* wx_w  = (const float*)d_in[8];
  const float* wx_b  = (const float*)d_in[9];
  const float* bnx_w = (const float*)d_in[10];
  const float* bnx_b = (const float*)d_in[11];
  const float* bnx_m = (const float*)d_in[12];
  const float* bnx_v = (const float*)d_in[13];
  const float* q_w   = (const float*)d_in[14];
  const float* q_b   = (const float*)d_in[15];
  const float* k_w   = (const float*)d_in[16];
  const float* k_b   = (const float*)d_in[17];
  const float* v_w   = (const float*)d_in[18];
  const float* v_b   = (const float*)d_in[19];
  const float* sa_g  = (const float*)d_in[20];
  const float* psi_w = (const float*)d_in[21];
  const float* psi_b = (const float*)d_in[22];
  const float* bnp_w = (const float*)d_in[23];
  const float* bnp_b = (const float*)d_in[24];
  const float* bnp_m = (const float*)d_in[25];
  const float* bnp_v = (const float*)d_in[26];
  float* out = (float*)d_out;

  char* ws = (char*)d_ws;
  unsigned short* cb = (unsigned short*)(ws + C_OFF);
  unsigned short* Qb = (unsigned short*)(ws + Q_OFF);
  unsigned short* Kb = (unsigned short*)(ws + K_OFF);
  unsigned short* Vb = (unsigned short*)(ws + V_OFF);
  unsigned short* Opart = (unsigned short*)(ws + OPART_OFF);
  float* mlb = (float*)(ws + ML_OFF);

  hipLaunchKernelGGL(conv_fused_kernel, dim3(1024), dim3(256), 0, stream,
                     g, x, wg_w, wg_b, bng_w, bng_b, bng_m, bng_v,
                     wx_w, wx_b, bnx_w, bnx_b, bnx_m, bnx_v,
                     q_w, q_b, k_w, k_b, v_w, v_b,
                     cb, Qb, Kb, Vb);

  hipLaunchKernelGGL(attn_partial_kernel, dim3(2048), dim3(256), 0, stream,
                     Qb, Kb, Vb, Opart, mlb);

  hipLaunchKernelGGL(combine_kernel, dim3(1024), dim3(256), 0, stream,
                     Opart, mlb, cb, x,
                     psi_w, psi_b, bnp_w, bnp_b, bnp_m, bnp_v, sa_g,
                     out);
}